// Round 4
// baseline (153.493 us; speedup 1.0000x reference)
//
#include <hip/hip_runtime.h>

// Problem dims: B=16, Q=64, K=512, DQ=DK=DV=512, H=256
#define LOG2E 1.4426950408889634f
#define TWO_LOG2E 2.8853900817779268f

typedef __attribute__((ext_vector_type(8))) short short8;   // bf16x8 MFMA frag
typedef __attribute__((ext_vector_type(4))) float f32x4;    // MFMA acc

__device__ __forceinline__ float e2x(float v) {
    return __builtin_amdgcn_exp2f(v * TWO_LOG2E);   // e^{2v}
}

// Exact fp32 -> (hi,lo) bf16 split, packed.
__device__ __forceinline__ void split2(float x, float y, unsigned& hi, unsigned& lo) {
    unsigned ux = __float_as_uint(x), uy = __float_as_uint(y);
    float hx = __uint_as_float(ux & 0xffff0000u);
    float hy = __uint_as_float(uy & 0xffff0000u);
    unsigned lx = __float_as_uint(x - hx), ly = __float_as_uint(y - hy);
    hi = (ux >> 16) | (uy & 0xffff0000u);
    lo = (lx >> 16) | (ly & 0xffff0000u);
}

// ---------------------------------------------------------------------------
// Kernel 0: W2T split/transposed weights (chunk-major DRAM layout, unchanged).
// ---------------------------------------------------------------------------
__global__ __launch_bounds__(256) void wprep_kernel(const float* __restrict__ Wq,
                                                    const float* __restrict__ Wk,
                                                    ushort* __restrict__ Wq2T,
                                                    ushort* __restrict__ Wk2T) {
    __shared__ float T[64][65];
    const float* W  = blockIdx.z ? Wk : Wq;
    ushort* W2T     = blockIdx.z ? Wk2T : Wq2T;
    const int t  = threadIdx.x;
    const int k0 = blockIdx.x * 64;
    const int n0 = blockIdx.y * 64;
#pragma unroll
    for (int p = 0; p < 4; ++p) {
        int u  = t + p * 256;
        int kk = u >> 4;
        int nf = (u & 15) * 4;
        float4 w = *reinterpret_cast<const float4*>(&W[(size_t)(k0 + kk) * 256 + n0 + nf]);
        T[nf + 0][kk] = w.x; T[nf + 1][kk] = w.y;
        T[nf + 2][kk] = w.z; T[nf + 3][kk] = w.w;
    }
    __syncthreads();
#pragma unroll
    for (int p = 0; p < 4; ++p) {
        int u  = t + p * 256;
        int n  = u >> 4;
        int kf = (u & 15) * 4;
        float a = T[n][kf], b = T[n][kf + 1], c = T[n][kf + 2], d = T[n][kf + 3];
        unsigned h01, l01, h23, l23;
        split2(a, b, h01, l01);
        split2(c, d, h23, l23);
        int kg   = k0 + kf;              // global k, multiple of 4
        int ng   = n0 + n;               // global n 0..255
        int tile = ng >> 6;
        int row  = ng & 63;
        int cc   = kg >> 5;
        int kpos = kg & 31;
        ushort* base = W2T + (size_t)(tile * 16 + cc) * 6144
                     + (kpos >> 3) * 512 + row * 8 + (kpos & 7);
        uint2 hi; hi.x = h01; hi.y = h23;
        uint2 lo; lo.x = l01; lo.y = l23;
        *reinterpret_cast<uint2*>(base)        = hi;   // s=0 (j = 0..3)
        *reinterpret_cast<uint2*>(base + 2048) = hi;   // s=1 (j = 4..7)
        *reinterpret_cast<uint2*>(base + 4096) = lo;   // s=2 (j = 8..11)
    }
}

// ---------------------------------------------------------------------------
// Kernel 1: fused MFMA projection (unchanged from round 3).
// ---------------------------------------------------------------------------
__global__ __launch_bounds__(256) void mfma_proj_kernel(const float* __restrict__ queries,
                                                        const float* __restrict__ keys,
                                                        const ushort* __restrict__ Wq2T,
                                                        const ushort* __restrict__ Wk2T,
                                                        float* __restrict__ Eq,
                                                        float* __restrict__ Ekp) {
    __shared__ float smemf[4736];            // 18944 B: Ah(6656) + B(12288); reused as Cs
    ushort* Ah = reinterpret_cast<ushort*>(smemf);           // [32 m][104 k'] padded
    ushort* Bl = reinterpret_cast<ushort*>(smemf) + 3328;    // [j 12][row 64][8 ushort]

    const int t    = threadIdx.x;
    const int mt   = blockIdx.x;
    const int Nb   = blockIdx.y * 64;
    const bool isQ = mt < 32;
    const int mloc = (isQ ? mt : mt - 32) * 32;
    const float4* Asrc4 = reinterpret_cast<const float4*>(isQ ? queries : keys)
                        + (size_t)mloc * 128;
    const ushort* W2T = isQ ? Wq2T : Wk2T;

    const int ln15 = t & 15;
    const int q    = (t >> 4) & 3;
    const int w    = t >> 6;
    const int wn   = w * 16;                 // wave n-offset within 64
    const int am   = t >> 3;
    const int ak   = t & 7;

    const char* gB[3];
#pragma unroll
    for (int i = 0; i < 3; ++i)
        gB[i] = reinterpret_cast<const char*>(W2T) + (size_t)(Nb >> 6) * 196608
              + i * 4096 + t * 16;

    f32x4 acc[2];
    acc[0] = (f32x4)0.0f;
    acc[1] = (f32x4)0.0f;

    float4 ra = Asrc4[(size_t)am * 128 + ak];

    for (int c = 0; c < 16; ++c) {
        __syncthreads();
#pragma unroll
        for (int i = 0; i < 3; ++i) {
            __builtin_amdgcn_global_load_lds(
                reinterpret_cast<const unsigned int*>(gB[i]),
                reinterpret_cast<unsigned int*>(
                    reinterpret_cast<char*>(smemf) + 6656 + i * 4096 + (t >> 6) * 1024),
                16, 0, 0);
            gB[i] += 12288;
        }
        {
            unsigned h01, l01, h23, l23;
            split2(ra.x, ra.y, h01, l01);
            split2(ra.z, ra.w, h23, l23);
            uint2 hi; hi.x = h01; hi.y = h23;
            uint2 lo; lo.x = l01; lo.y = l23;
            ushort* row = Ah + am * 104 + ak * 4;
            *reinterpret_cast<uint2*>(row)      = hi;   // s=0
            *reinterpret_cast<uint2*>(row + 32) = lo;   // s=1
            *reinterpret_cast<uint2*>(row + 64) = hi;   // s=2
        }
        if (c < 15) ra = Asrc4[(size_t)am * 128 + (c + 1) * 8 + ak];
        __syncthreads();
#pragma unroll
        for (int s = 0; s < 3; ++s) {
            short8 af[2], bf;
#pragma unroll
            for (int fm = 0; fm < 2; ++fm)
                af[fm] = *reinterpret_cast<const short8*>(
                    Ah + (fm * 16 + ln15) * 104 + s * 32 + q * 8);
            bf = *reinterpret_cast<const short8*>(
                Bl + (s * 4 + q) * 512 + (wn + ln15) * 8);
#pragma unroll
            for (int fm = 0; fm < 2; ++fm)
                acc[fm] = __builtin_amdgcn_mfma_f32_16x16x32_bf16(
                    af[fm], bf, acc[fm], 0, 0, 0);
        }
    }

    if (isQ) {
#pragma unroll
        for (int fm = 0; fm < 2; ++fm)
#pragma unroll
            for (int r = 0; r < 4; ++r) {
                int row = mloc + fm * 16 + q * 4 + r;
                int col = Nb + wn + ln15;
                Eq[(size_t)row * 256 + col] = e2x(acc[fm][r]);
            }
    } else {
        __syncthreads();
        float (*Cs)[33] = reinterpret_cast<float(*)[33]>(smemf);  // [n 64][m 32]
#pragma unroll
        for (int fm = 0; fm < 2; ++fm)
#pragma unroll
            for (int r = 0; r < 4; ++r) {
                int m_l = fm * 16 + q * 4 + r;
                int n_l = wn + ln15;
                Cs[n_l][m_l] = acc[fm][r];
            }
        __syncthreads();
        const int b      = mloc >> 9;
        const int k0h    = (mloc & 511) >> 1;
        const int h2base = Nb >> 1;
        float4* out4 = reinterpret_cast<float4*>(Ekp);
#pragma unroll
        for (int p = 0; p < 2; ++p) {
            int u   = t + p * 256;           // 0..511
            int h2r = u >> 4;                // 0..31
            int kp  = u & 15;                // 0..15
            int kk  = kp * 2;
            float4 o;
            o.x = e2x(Cs[2 * h2r    ][kk    ]);
            o.y = e2x(Cs[2 * h2r + 1][kk    ]);
            o.z = e2x(Cs[2 * h2r    ][kk + 1]);
            o.w = e2x(Cs[2 * h2r + 1][kk + 1]);
            out4[(size_t)b * 32768 + (size_t)(h2base + h2r) * 256 + k0h + kp] = o;
        }
    }
}

// ---------------------------------------------------------------------------
// Kernel 2: FUSED score + no-max softmax + PV, fully block-local (no atomics).
// Block = (qt, b): 4 q-rows x all 512 k. Grid (16, 16) = 256 blocks, 256 thr.
// Phase A: thread owns k-cols {t, t+256}; loops 128 h2-pairs (same verified
//          tanh algebra; Eq/Wv broadcast from LDS, Ekp streamed, coalesced).
// Phase B: E = exp(-2*acc) (scores bounded |s|<~26 -> no max-sub needed;
//          masked k -> E=0 exactly); block-reduce denom; P = E/denom in LDS.
// Phase C: thread owns v-cols {2t, 2t+1}; P float4 LDS-broadcast, V float2
//          streamed from L2 (16 blocks share V[b] = 1 MB).
// ---------------------------------------------------------------------------
__global__ __launch_bounds__(256) void attn_kernel(
        const float* __restrict__ Eq, const float* __restrict__ Ekp,
        const float* __restrict__ Wv, const int* __restrict__ valid_lens,
        const float* __restrict__ values, float* __restrict__ out) {
    __shared__ __align__(16) float Eqs[4][256];   // 4 KB
    __shared__ float Wvs[256];                    // 1 KB
    __shared__ __align__(16) float P[4][512];     // 8 KB
    __shared__ float Sd[4][4];

    const int t  = threadIdx.x;
    const int q0 = blockIdx.x * 4;
    const int b  = blockIdx.y;

    // stage Eq rows (4 x 256 floats = 256 float4) + Wv
    const float4* eq4 = reinterpret_cast<const float4*>(Eq + (size_t)(b * 64 + q0) * 256);
    *reinterpret_cast<float4*>(&Eqs[t >> 6][(t & 63) * 4]) = eq4[t];
    Wvs[t] = Wv[t];
    __syncthreads();

    // ---- phase A: raw scores for k = t and k = t + 256 ----
    const float2* ekp2 = reinterpret_cast<const float2*>(Ekp) + (size_t)b * 65536 + t;
    float accA[4] = {0.f, 0.f, 0.f, 0.f};
    float accB[4] = {0.f, 0.f, 0.f, 0.f};
#pragma unroll 4
    for (int h2 = 0; h2 < 128; ++h2) {
        float2 ekA = ekp2[h2 * 512];
        float2 ekB = ekp2[h2 * 512 + 256];
        float2 wv  = *reinterpret_cast<const float2*>(&Wvs[2 * h2]);
#pragma unroll
        for (int q = 0; q < 4; ++q) {
            float2 e = *reinterpret_cast<const float2*>(&Eqs[q][2 * h2]);
            float a0 = fmaf(e.x, ekA.x, 1.0f);
            float a1 = fmaf(e.y, ekA.y, 1.0f);
            accA[q] = fmaf(fmaf(wv.y, a0, wv.x * a1),
                           __builtin_amdgcn_rcpf(a0 * a1), accA[q]);
            float b0 = fmaf(e.x, ekB.x, 1.0f);
            float b1 = fmaf(e.y, ekB.y, 1.0f);
            accB[q] = fmaf(fmaf(wv.y, b0, wv.x * b1),
                           __builtin_amdgcn_rcpf(b0 * b1), accB[q]);
        }
    }

    // ---- phase B: masked exp (no max-sub), denominator, normalized P ----
    const int vl = valid_lens[b];
    float EA[4], EB[4], part[4];
#pragma unroll
    for (int q = 0; q < 4; ++q) {
        float sA = -2.0f * accA[q];
        float sB = -2.0f * accB[q];
        EA[q] = (t       < vl) ? __builtin_amdgcn_exp2f(sA * LOG2E) : 0.0f;
        EB[q] = (t + 256 < vl) ? __builtin_amdgcn_exp2f(sB * LOG2E) : 0.0f;
        part[q] = EA[q] + EB[q];
    }
#pragma unroll
    for (int off = 32; off > 0; off >>= 1)
#pragma unroll
        for (int q = 0; q < 4; ++q) part[q] += __shfl_xor(part[q], off);
    if ((t & 63) == 0) {
#pragma unroll
        for (int q = 0; q < 4; ++q) Sd[t >> 6][q] = part[q];
    }
    __syncthreads();
#pragma unroll
    for (int q = 0; q < 4; ++q) {
        float inv = 1.0f / ((Sd[0][q] + Sd[1][q]) + (Sd[2][q] + Sd[3][q]));
        P[q][t]       = EA[q] * inv;
        P[q][t + 256] = EB[q] * inv;
    }
    __syncthreads();

    // ---- phase C: PV. out rows q0..q0+3, cols {2t, 2t+1} ----
    const float2* V2 = reinterpret_cast<const float2*>(values) + (size_t)b * 131072 + t;
    float2 av[4];
#pragma unroll
    for (int q = 0; q < 4; ++q) av[q] = make_float2(0.f, 0.f);

#pragma unroll 4
    for (int k4 = 0; k4 < 128; ++k4) {
        float2 v0 = V2[(size_t)(k4 * 4 + 0) * 256];
        float2 v1 = V2[(size_t)(k4 * 4 + 1) * 256];
        float2 v2 = V2[(size_t)(k4 * 4 + 2) * 256];
        float2 v3 = V2[(size_t)(k4 * 4 + 3) * 256];
#pragma unroll
        for (int q = 0; q < 4; ++q) {
            float4 p = *reinterpret_cast<const float4*>(&P[q][k4 * 4]);
            av[q].x = fmaf(p.x, v0.x, av[q].x); av[q].y = fmaf(p.x, v0.y, av[q].y);
            av[q].x = fmaf(p.y, v1.x, av[q].x); av[q].y = fmaf(p.y, v1.y, av[q].y);
            av[q].x = fmaf(p.z, v2.x, av[q].x); av[q].y = fmaf(p.z, v2.y, av[q].y);
            av[q].x = fmaf(p.w, v3.x, av[q].x); av[q].y = fmaf(p.w, v3.y, av[q].y);
        }
    }

    float* ob = out + (size_t)(b * 64 + q0) * 512 + 2 * t;
#pragma unroll
    for (int q = 0; q < 4; ++q)
        *reinterpret_cast<float2*>(ob + (size_t)q * 512) = av[q];
}

// ---------------------------------------------------------------------------
extern "C" void kernel_launch(void* const* d_in, const int* in_sizes, int n_in,
                              void* d_out, int out_size, void* d_ws, size_t ws_size,
                              hipStream_t stream) {
    (void)in_sizes; (void)n_in; (void)out_size; (void)ws_size;
    const float* queries    = (const float*)d_in[0];   // [16,64,512]
    const float* keys       = (const float*)d_in[1];   // [16,512,512]
    const float* values     = (const float*)d_in[2];   // [16,512,512]
    const int*   valid_lens = (const int*)d_in[3];     // [16]
    const float* Wq         = (const float*)d_in[4];   // [512,256]
    const float* Wk         = (const float*)d_in[5];   // [512,256]
    const float* Wv         = (const float*)d_in[6];   // [256]
    float* out = (float*)d_out;                        // [16,64,512]

    float* ws     = (float*)d_ws;
    float* Eq     = ws;                         // [1024][256]        1 MB
    float* Ekp    = ws + 262144;                // [16][128][512][2]  8 MB
    ushort* Wq2T  = (ushort*)(ws + 2883584);    // [4][16][12][64][8] 0.75 MB
    ushort* Wk2T  = Wq2T + 393216;              // same layout        0.75 MB

    hipLaunchKernelGGL(wprep_kernel, dim3(8, 4, 2), dim3(256), 0, stream,
                       Wq, Wk, Wq2T, Wk2T);
    hipLaunchKernelGGL(mfma_proj_kernel, dim3(288, 4), dim3(256), 0, stream,
                       queries, keys, Wq2T, Wk2T, Eq, Ekp);
    hipLaunchKernelGGL(attn_kernel, dim3(16, 16), dim3(256), 0, stream,
                       Eq, Ekp, Wv, valid_lens, values, out);
}

// Round 5
// 146.980 us; speedup vs baseline: 1.0443x; 1.0443x over previous
//
#include <hip/hip_runtime.h>

// Problem dims: B=16, Q=64, K=512, DQ=DK=DV=512, H=256
#define LOG2E 1.4426950408889634f
#define TWO_LOG2E 2.8853900817779268f

typedef __attribute__((ext_vector_type(8))) short short8;   // bf16x8 MFMA frag
typedef __attribute__((ext_vector_type(4))) float f32x4;    // MFMA acc

__device__ __forceinline__ float e2x(float v) {
    return __builtin_amdgcn_exp2f(v * TWO_LOG2E);   // e^{2v}
}

// Exact fp32 -> (hi,lo) bf16 split, packed.
__device__ __forceinline__ void split2(float x, float y, unsigned& hi, unsigned& lo) {
    unsigned ux = __float_as_uint(x), uy = __float_as_uint(y);
    float hx = __uint_as_float(ux & 0xffff0000u);
    float hy = __uint_as_float(uy & 0xffff0000u);
    unsigned lx = __float_as_uint(x - hx), ly = __float_as_uint(y - hy);
    hi = (ux >> 16) | (uy & 0xffff0000u);
    lo = (lx >> 16) | (ly & 0xffff0000u);
}

// ---------------------------------------------------------------------------
// Kernel 0: W2T split/transposed weights (chunk-major DRAM layout, unchanged).
// ---------------------------------------------------------------------------
__global__ __launch_bounds__(256) void wprep_kernel(const float* __restrict__ Wq,
                                                    const float* __restrict__ Wk,
                                                    ushort* __restrict__ Wq2T,
                                                    ushort* __restrict__ Wk2T) {
    __shared__ float T[64][65];
    const float* W  = blockIdx.z ? Wk : Wq;
    ushort* W2T     = blockIdx.z ? Wk2T : Wq2T;
    const int t  = threadIdx.x;
    const int k0 = blockIdx.x * 64;
    const int n0 = blockIdx.y * 64;
#pragma unroll
    for (int p = 0; p < 4; ++p) {
        int u  = t + p * 256;
        int kk = u >> 4;
        int nf = (u & 15) * 4;
        float4 w = *reinterpret_cast<const float4*>(&W[(size_t)(k0 + kk) * 256 + n0 + nf]);
        T[nf + 0][kk] = w.x; T[nf + 1][kk] = w.y;
        T[nf + 2][kk] = w.z; T[nf + 3][kk] = w.w;
    }
    __syncthreads();
#pragma unroll
    for (int p = 0; p < 4; ++p) {
        int u  = t + p * 256;
        int n  = u >> 4;
        int kf = (u & 15) * 4;
        float a = T[n][kf], b = T[n][kf + 1], c = T[n][kf + 2], d = T[n][kf + 3];
        unsigned h01, l01, h23, l23;
        split2(a, b, h01, l01);
        split2(c, d, h23, l23);
        int kg   = k0 + kf;              // global k, multiple of 4
        int ng   = n0 + n;               // global n 0..255
        int tile = ng >> 6;
        int row  = ng & 63;
        int cc   = kg >> 5;
        int kpos = kg & 31;
        ushort* base = W2T + (size_t)(tile * 16 + cc) * 6144
                     + (kpos >> 3) * 512 + row * 8 + (kpos & 7);
        uint2 hi; hi.x = h01; hi.y = h23;
        uint2 lo; lo.x = l01; lo.y = l23;
        *reinterpret_cast<uint2*>(base)        = hi;   // s=0 (j = 0..3)
        *reinterpret_cast<uint2*>(base + 2048) = hi;   // s=1 (j = 4..7)
        *reinterpret_cast<uint2*>(base + 4096) = lo;   // s=2 (j = 8..11)
    }
}

// ---------------------------------------------------------------------------
// Kernel 1: fused MFMA projection (unchanged).
// ---------------------------------------------------------------------------
__global__ __launch_bounds__(256) void mfma_proj_kernel(const float* __restrict__ queries,
                                                        const float* __restrict__ keys,
                                                        const ushort* __restrict__ Wq2T,
                                                        const ushort* __restrict__ Wk2T,
                                                        float* __restrict__ Eq,
                                                        float* __restrict__ Ekp) {
    __shared__ float smemf[4736];            // 18944 B: Ah(6656) + B(12288); reused as Cs
    ushort* Ah = reinterpret_cast<ushort*>(smemf);           // [32 m][104 k'] padded
    ushort* Bl = reinterpret_cast<ushort*>(smemf) + 3328;    // [j 12][row 64][8 ushort]

    const int t    = threadIdx.x;
    const int mt   = blockIdx.x;
    const int Nb   = blockIdx.y * 64;
    const bool isQ = mt < 32;
    const int mloc = (isQ ? mt : mt - 32) * 32;
    const float4* Asrc4 = reinterpret_cast<const float4*>(isQ ? queries : keys)
                        + (size_t)mloc * 128;
    const ushort* W2T = isQ ? Wq2T : Wk2T;

    const int ln15 = t & 15;
    const int q    = (t >> 4) & 3;
    const int w    = t >> 6;
    const int wn   = w * 16;                 // wave n-offset within 64
    const int am   = t >> 3;
    const int ak   = t & 7;

    const char* gB[3];
#pragma unroll
    for (int i = 0; i < 3; ++i)
        gB[i] = reinterpret_cast<const char*>(W2T) + (size_t)(Nb >> 6) * 196608
              + i * 4096 + t * 16;

    f32x4 acc[2];
    acc[0] = (f32x4)0.0f;
    acc[1] = (f32x4)0.0f;

    float4 ra = Asrc4[(size_t)am * 128 + ak];

    for (int c = 0; c < 16; ++c) {
        __syncthreads();
#pragma unroll
        for (int i = 0; i < 3; ++i) {
            __builtin_amdgcn_global_load_lds(
                reinterpret_cast<const unsigned int*>(gB[i]),
                reinterpret_cast<unsigned int*>(
                    reinterpret_cast<char*>(smemf) + 6656 + i * 4096 + (t >> 6) * 1024),
                16, 0, 0);
            gB[i] += 12288;
        }
        {
            unsigned h01, l01, h23, l23;
            split2(ra.x, ra.y, h01, l01);
            split2(ra.z, ra.w, h23, l23);
            uint2 hi; hi.x = h01; hi.y = h23;
            uint2 lo; lo.x = l01; lo.y = l23;
            ushort* row = Ah + am * 104 + ak * 4;
            *reinterpret_cast<uint2*>(row)      = hi;   // s=0
            *reinterpret_cast<uint2*>(row + 32) = lo;   // s=1
            *reinterpret_cast<uint2*>(row + 64) = hi;   // s=2
        }
        if (c < 15) ra = Asrc4[(size_t)am * 128 + (c + 1) * 8 + ak];
        __syncthreads();
#pragma unroll
        for (int s = 0; s < 3; ++s) {
            short8 af[2], bf;
#pragma unroll
            for (int fm = 0; fm < 2; ++fm)
                af[fm] = *reinterpret_cast<const short8*>(
                    Ah + (fm * 16 + ln15) * 104 + s * 32 + q * 8);
            bf = *reinterpret_cast<const short8*>(
                Bl + (s * 4 + q) * 512 + (wn + ln15) * 8);
#pragma unroll
            for (int fm = 0; fm < 2; ++fm)
                acc[fm] = __builtin_amdgcn_mfma_f32_16x16x32_bf16(
                    af[fm], bf, acc[fm], 0, 0, 0);
        }
    }

    if (isQ) {
#pragma unroll
        for (int fm = 0; fm < 2; ++fm)
#pragma unroll
            for (int r = 0; r < 4; ++r) {
                int row = mloc + fm * 16 + q * 4 + r;
                int col = Nb + wn + ln15;
                Eq[(size_t)row * 256 + col] = e2x(acc[fm][r]);
            }
    } else {
        __syncthreads();
        float (*Cs)[33] = reinterpret_cast<float(*)[33]>(smemf);  // [n 64][m 32]
#pragma unroll
        for (int fm = 0; fm < 2; ++fm)
#pragma unroll
            for (int r = 0; r < 4; ++r) {
                int m_l = fm * 16 + q * 4 + r;
                int n_l = wn + ln15;
                Cs[n_l][m_l] = acc[fm][r];
            }
        __syncthreads();
        const int b      = mloc >> 9;
        const int k0h    = (mloc & 511) >> 1;
        const int h2base = Nb >> 1;
        float4* out4 = reinterpret_cast<float4*>(Ekp);
#pragma unroll
        for (int p = 0; p < 2; ++p) {
            int u   = t + p * 256;           // 0..511
            int h2r = u >> 4;                // 0..31
            int kp  = u & 15;                // 0..15
            int kk  = kp * 2;
            float4 o;
            o.x = e2x(Cs[2 * h2r    ][kk    ]);
            o.y = e2x(Cs[2 * h2r + 1][kk    ]);
            o.z = e2x(Cs[2 * h2r    ][kk + 1]);
            o.w = e2x(Cs[2 * h2r + 1][kk + 1]);
            out4[(size_t)b * 32768 + (size_t)(h2base + h2r) * 256 + k0h + kp] = o;
        }
    }
}

// ---------------------------------------------------------------------------
// Kernel 2 v2: FUSED score + no-max softmax + PV, block-local.
// CHANGES vs round 4:
//  * 512 threads/block (2 waves/SIMD, 2x TLP for latency hiding).
//  * XCD-bijective work remap: r=lid&7, j=lid>>3, b=r+8*(j&1), qt=j>>1 --
//    all 16 qt-blocks of batch b land on XCD b&7 (linear-id round-robin),
//    so Ekp[b] (0.5 MB) + V[b] (1 MB) stay L2-resident (2 batches = 3 MB/XCD).
// Phase A: thread owns k-col t (512 thr <-> 512 k); 128 h2-pairs.
// Phase B: no-max softmax; 8-wave shfl reduce + LDS combine; P[4][512].
// Phase C: thread = (v-pair t&255, k-half t>>8); float2 V loads; LDS combine.
// ---------------------------------------------------------------------------
__global__ __launch_bounds__(512) void attn_kernel(
        const float* __restrict__ Eq, const float* __restrict__ Ekp,
        const float* __restrict__ Wv, const int* __restrict__ valid_lens,
        const float* __restrict__ values, float* __restrict__ out) {
    __shared__ __align__(16) float Eqs[4][256];   // 4 KB
    __shared__ float Wvs[256];                    // 1 KB
    __shared__ __align__(16) float P[4][512];     // 8 KB
    __shared__ float Sd[8][4];                    // wave partial denoms
    __shared__ __align__(16) float2 Pc[4][256];   // 8 KB, phase-C combine

    const int t   = threadIdx.x;
    const int lid = blockIdx.x;
    // XCD-bijective remap (8 XCDs, 256 blocks): batch b pinned to XCD b&7.
    const int r  = lid & 7;
    const int j  = lid >> 3;            // 0..31
    const int b  = r + 8 * (j & 1);     // 0..15
    const int q0 = (j >> 1) * 4;        // 0..60

    // stage Eq rows (4 x 256 floats) + Wv with the first 256 threads
    if (t < 256) {
        const float4* eq4 = reinterpret_cast<const float4*>(Eq + (size_t)(b * 64 + q0) * 256);
        *reinterpret_cast<float4*>(&Eqs[t >> 6][(t & 63) * 4]) = eq4[t];
        Wvs[t] = Wv[t];
    }
    __syncthreads();

    // ---- phase A: raw score for k = t ----
    const float2* ekp2 = reinterpret_cast<const float2*>(Ekp) + (size_t)b * 65536 + t;
    float acc[4] = {0.f, 0.f, 0.f, 0.f};
#pragma unroll 8
    for (int h2 = 0; h2 < 128; ++h2) {
        float2 ek = ekp2[h2 * 512];
        float2 wv = *reinterpret_cast<const float2*>(&Wvs[2 * h2]);
#pragma unroll
        for (int q = 0; q < 4; ++q) {
            float2 e = *reinterpret_cast<const float2*>(&Eqs[q][2 * h2]);
            float a0 = fmaf(e.x, ek.x, 1.0f);
            float a1 = fmaf(e.y, ek.y, 1.0f);
            acc[q] = fmaf(fmaf(wv.y, a0, wv.x * a1),
                          __builtin_amdgcn_rcpf(a0 * a1), acc[q]);
        }
    }

    // ---- phase B: masked exp (no max-sub), block denom, normalized P ----
    const int vl = valid_lens[b];
    float E[4], part[4];
#pragma unroll
    for (int q = 0; q < 4; ++q) {
        float s = -2.0f * acc[q];
        E[q] = (t < vl) ? __builtin_amdgcn_exp2f(s * LOG2E) : 0.0f;
        part[q] = E[q];
    }
#pragma unroll
    for (int off = 32; off > 0; off >>= 1)
#pragma unroll
        for (int q = 0; q < 4; ++q) part[q] += __shfl_xor(part[q], off);
    if ((t & 63) == 0) {
#pragma unroll
        for (int q = 0; q < 4; ++q) Sd[t >> 6][q] = part[q];
    }
    __syncthreads();
#pragma unroll
    for (int q = 0; q < 4; ++q) {
        float d = ((Sd[0][q] + Sd[1][q]) + (Sd[2][q] + Sd[3][q]))
                + ((Sd[4][q] + Sd[5][q]) + (Sd[6][q] + Sd[7][q]));
        P[q][t] = E[q] * (1.0f / d);
    }
    __syncthreads();

    // ---- phase C: PV. thread = (v-pair v2c, k-half kh); 256 k each ----
    const int v2c = t & 255;            // v-cols {2*v2c, 2*v2c+1}
    const int kh  = t >> 8;             // 0..1 -> k in [kh*256, kh*256+256)
    const float2* V2 = reinterpret_cast<const float2*>(values)
                     + (size_t)b * 131072 + (size_t)(kh * 256) * 256 + v2c;
    float2 av[4];
#pragma unroll
    for (int q = 0; q < 4; ++q) av[q] = make_float2(0.f, 0.f);

#pragma unroll 4
    for (int k4 = 0; k4 < 64; ++k4) {
        float2 v0 = V2[(size_t)(k4 * 4 + 0) * 256];
        float2 v1 = V2[(size_t)(k4 * 4 + 1) * 256];
        float2 v2 = V2[(size_t)(k4 * 4 + 2) * 256];
        float2 v3 = V2[(size_t)(k4 * 4 + 3) * 256];
#pragma unroll
        for (int q = 0; q < 4; ++q) {
            float4 p = *reinterpret_cast<const float4*>(&P[q][kh * 256 + k4 * 4]);
            av[q].x = fmaf(p.x, v0.x, av[q].x); av[q].y = fmaf(p.x, v0.y, av[q].y);
            av[q].x = fmaf(p.y, v1.x, av[q].x); av[q].y = fmaf(p.y, v1.y, av[q].y);
            av[q].x = fmaf(p.z, v2.x, av[q].x); av[q].y = fmaf(p.z, v2.y, av[q].y);
            av[q].x = fmaf(p.w, v3.x, av[q].x); av[q].y = fmaf(p.w, v3.y, av[q].y);
        }
    }

    if (kh == 1) {
#pragma unroll
        for (int q = 0; q < 4; ++q) Pc[q][v2c] = av[q];
    }
    __syncthreads();
    if (kh == 0) {
        float* ob = out + (size_t)(b * 64 + q0) * 512 + 2 * v2c;
#pragma unroll
        for (int q = 0; q < 4; ++q) {
            float2 o = Pc[q][v2c];
            o.x += av[q].x; o.y += av[q].y;
            *reinterpret_cast<float2*>(ob + (size_t)q * 512) = o;
        }
    }
}

// ---------------------------------------------------------------------------
extern "C" void kernel_launch(void* const* d_in, const int* in_sizes, int n_in,
                              void* d_out, int out_size, void* d_ws, size_t ws_size,
                              hipStream_t stream) {
    (void)in_sizes; (void)n_in; (void)out_size; (void)ws_size;
    const float* queries    = (const float*)d_in[0];   // [16,64,512]
    const float* keys       = (const float*)d_in[1];   // [16,512,512]
    const float* values     = (const float*)d_in[2];   // [16,512,512]
    const int*   valid_lens = (const int*)d_in[3];     // [16]
    const float* Wq         = (const float*)d_in[4];   // [512,256]
    const float* Wk         = (const float*)d_in[5];   // [512,256]
    const float* Wv         = (const float*)d_in[6];   // [256]
    float* out = (float*)d_out;                        // [16,64,512]

    float* ws     = (float*)d_ws;
    float* Eq     = ws;                         // [1024][256]        1 MB
    float* Ekp    = ws + 262144;                // [16][128][512][2]  8 MB
    ushort* Wq2T  = (ushort*)(ws + 2883584);    // [4][16][12][64][8] 0.75 MB
    ushort* Wk2T  = Wq2T + 393216;              // same layout        0.75 MB

    hipLaunchKernelGGL(wprep_kernel, dim3(8, 4, 2), dim3(256), 0, stream,
                       Wq, Wk, Wq2T, Wk2T);
    hipLaunchKernelGGL(mfma_proj_kernel, dim3(288, 4), dim3(256), 0, stream,
                       queries, keys, Wq2T, Wk2T, Eq, Ekp);
    hipLaunchKernelGGL(attn_kernel, dim3(256), dim3(512), 0, stream,
                       Eq, Ekp, Wv, valid_lens, values, out);
}

// Round 6
// 140.654 us; speedup vs baseline: 1.0913x; 1.0450x over previous
//
#include <hip/hip_runtime.h>

// Problem dims: B=16, Q=64, K=512, DQ=DK=DV=512, H=256
#define LOG2E 1.4426950408889634f
#define TWO_LOG2E 2.8853900817779268f

typedef __attribute__((ext_vector_type(8))) short short8;   // bf16x8 MFMA frag
typedef __attribute__((ext_vector_type(4))) float f32x4;    // MFMA acc

__device__ __forceinline__ float e2x(float v) {
    return __builtin_amdgcn_exp2f(v * TWO_LOG2E);   // e^{2v}
}

// Exact fp32 -> (hi,lo) bf16 split, packed.
__device__ __forceinline__ void split2(float x, float y, unsigned& hi, unsigned& lo) {
    unsigned ux = __float_as_uint(x), uy = __float_as_uint(y);
    float hx = __uint_as_float(ux & 0xffff0000u);
    float hy = __uint_as_float(uy & 0xffff0000u);
    unsigned lx = __float_as_uint(x - hx), ly = __float_as_uint(y - hy);
    hi = (ux >> 16) | (uy & 0xffff0000u);
    lo = (lx >> 16) | (ly & 0xffff0000u);
}

// ---------------------------------------------------------------------------
// Kernel 0: W2T split/transposed weights (chunk-major DRAM layout, unchanged).
// ---------------------------------------------------------------------------
__global__ __launch_bounds__(256) void wprep_kernel(const float* __restrict__ Wq,
                                                    const float* __restrict__ Wk,
                                                    ushort* __restrict__ Wq2T,
                                                    ushort* __restrict__ Wk2T) {
    __shared__ float T[64][65];
    const float* W  = blockIdx.z ? Wk : Wq;
    ushort* W2T     = blockIdx.z ? Wk2T : Wq2T;
    const int t  = threadIdx.x;
    const int k0 = blockIdx.x * 64;
    const int n0 = blockIdx.y * 64;
#pragma unroll
    for (int p = 0; p < 4; ++p) {
        int u  = t + p * 256;
        int kk = u >> 4;
        int nf = (u & 15) * 4;
        float4 w = *reinterpret_cast<const float4*>(&W[(size_t)(k0 + kk) * 256 + n0 + nf]);
        T[nf + 0][kk] = w.x; T[nf + 1][kk] = w.y;
        T[nf + 2][kk] = w.z; T[nf + 3][kk] = w.w;
    }
    __syncthreads();
#pragma unroll
    for (int p = 0; p < 4; ++p) {
        int u  = t + p * 256;
        int n  = u >> 4;
        int kf = (u & 15) * 4;
        float a = T[n][kf], b = T[n][kf + 1], c = T[n][kf + 2], d = T[n][kf + 3];
        unsigned h01, l01, h23, l23;
        split2(a, b, h01, l01);
        split2(c, d, h23, l23);
        int kg   = k0 + kf;              // global k, multiple of 4
        int ng   = n0 + n;               // global n 0..255
        int tile = ng >> 6;
        int row  = ng & 63;
        int cc   = kg >> 5;
        int kpos = kg & 31;
        ushort* base = W2T + (size_t)(tile * 16 + cc) * 6144
                     + (kpos >> 3) * 512 + row * 8 + (kpos & 7);
        uint2 hi; hi.x = h01; hi.y = h23;
        uint2 lo; lo.x = l01; lo.y = l23;
        *reinterpret_cast<uint2*>(base)        = hi;   // s=0 (j = 0..3)
        *reinterpret_cast<uint2*>(base + 2048) = hi;   // s=1 (j = 4..7)
        *reinterpret_cast<uint2*>(base + 4096) = lo;   // s=2 (j = 8..11)
    }
}

// ---------------------------------------------------------------------------
// Kernel 1: fused MFMA projection (unchanged).
// ---------------------------------------------------------------------------
__global__ __launch_bounds__(256) void mfma_proj_kernel(const float* __restrict__ queries,
                                                        const float* __restrict__ keys,
                                                        const ushort* __restrict__ Wq2T,
                                                        const ushort* __restrict__ Wk2T,
                                                        float* __restrict__ Eq,
                                                        float* __restrict__ Ekp) {
    __shared__ float smemf[4736];            // 18944 B: Ah(6656) + B(12288); reused as Cs
    ushort* Ah = reinterpret_cast<ushort*>(smemf);           // [32 m][104 k'] padded
    ushort* Bl = reinterpret_cast<ushort*>(smemf) + 3328;    // [j 12][row 64][8 ushort]

    const int t    = threadIdx.x;
    const int mt   = blockIdx.x;
    const int Nb   = blockIdx.y * 64;
    const bool isQ = mt < 32;
    const int mloc = (isQ ? mt : mt - 32) * 32;
    const float4* Asrc4 = reinterpret_cast<const float4*>(isQ ? queries : keys)
                        + (size_t)mloc * 128;
    const ushort* W2T = isQ ? Wq2T : Wk2T;

    const int ln15 = t & 15;
    const int q    = (t >> 4) & 3;
    const int w    = t >> 6;
    const int wn   = w * 16;                 // wave n-offset within 64
    const int am   = t >> 3;
    const int ak   = t & 7;

    const char* gB[3];
#pragma unroll
    for (int i = 0; i < 3; ++i)
        gB[i] = reinterpret_cast<const char*>(W2T) + (size_t)(Nb >> 6) * 196608
              + i * 4096 + t * 16;

    f32x4 acc[2];
    acc[0] = (f32x4)0.0f;
    acc[1] = (f32x4)0.0f;

    float4 ra = Asrc4[(size_t)am * 128 + ak];

    for (int c = 0; c < 16; ++c) {
        __syncthreads();
#pragma unroll
        for (int i = 0; i < 3; ++i) {
            __builtin_amdgcn_global_load_lds(
                reinterpret_cast<const unsigned int*>(gB[i]),
                reinterpret_cast<unsigned int*>(
                    reinterpret_cast<char*>(smemf) + 6656 + i * 4096 + (t >> 6) * 1024),
                16, 0, 0);
            gB[i] += 12288;
        }
        {
            unsigned h01, l01, h23, l23;
            split2(ra.x, ra.y, h01, l01);
            split2(ra.z, ra.w, h23, l23);
            uint2 hi; hi.x = h01; hi.y = h23;
            uint2 lo; lo.x = l01; lo.y = l23;
            ushort* row = Ah + am * 104 + ak * 4;
            *reinterpret_cast<uint2*>(row)      = hi;   // s=0
            *reinterpret_cast<uint2*>(row + 32) = lo;   // s=1
            *reinterpret_cast<uint2*>(row + 64) = hi;   // s=2
        }
        if (c < 15) ra = Asrc4[(size_t)am * 128 + (c + 1) * 8 + ak];
        __syncthreads();
#pragma unroll
        for (int s = 0; s < 3; ++s) {
            short8 af[2], bf;
#pragma unroll
            for (int fm = 0; fm < 2; ++fm)
                af[fm] = *reinterpret_cast<const short8*>(
                    Ah + (fm * 16 + ln15) * 104 + s * 32 + q * 8);
            bf = *reinterpret_cast<const short8*>(
                Bl + (s * 4 + q) * 512 + (wn + ln15) * 8);
#pragma unroll
            for (int fm = 0; fm < 2; ++fm)
                acc[fm] = __builtin_amdgcn_mfma_f32_16x16x32_bf16(
                    af[fm], bf, acc[fm], 0, 0, 0);
        }
    }

    if (isQ) {
#pragma unroll
        for (int fm = 0; fm < 2; ++fm)
#pragma unroll
            for (int r = 0; r < 4; ++r) {
                int row = mloc + fm * 16 + q * 4 + r;
                int col = Nb + wn + ln15;
                Eq[(size_t)row * 256 + col] = e2x(acc[fm][r]);
            }
    } else {
        __syncthreads();
        float (*Cs)[33] = reinterpret_cast<float(*)[33]>(smemf);  // [n 64][m 32]
#pragma unroll
        for (int fm = 0; fm < 2; ++fm)
#pragma unroll
            for (int r = 0; r < 4; ++r) {
                int m_l = fm * 16 + q * 4 + r;
                int n_l = wn + ln15;
                Cs[n_l][m_l] = acc[fm][r];
            }
        __syncthreads();
        const int b      = mloc >> 9;
        const int k0h    = (mloc & 511) >> 1;
        const int h2base = Nb >> 1;
        float4* out4 = reinterpret_cast<float4*>(Ekp);
#pragma unroll
        for (int p = 0; p < 2; ++p) {
            int u   = t + p * 256;           // 0..511
            int h2r = u >> 4;                // 0..31
            int kp  = u & 15;                // 0..15
            int kk  = kp * 2;
            float4 o;
            o.x = e2x(Cs[2 * h2r    ][kk    ]);
            o.y = e2x(Cs[2 * h2r + 1][kk    ]);
            o.z = e2x(Cs[2 * h2r    ][kk + 1]);
            o.w = e2x(Cs[2 * h2r + 1][kk + 1]);
            out4[(size_t)b * 32768 + (size_t)(h2base + h2r) * 256 + k0h + kp] = o;
        }
    }
}

// ---------------------------------------------------------------------------
// Kernel 2 v3: FUSED score + no-max softmax + PV, block-local.
// CHANGES vs round 5: 1024 threads/block (16 waves/CU = 4/SIMD, 2x TLP),
// same 256-block grid + XCD-bijective remap (keeps FETCH at ~13 MB).
// Phase A: thread = (k = t&511, hh = t>>9); hh walks 64 of 128 h2-pairs;
//          partials combined via 16 KB LDS (Ubuf as Sacc[2][4][512]).
// Phase B: half hh exponentiates q-rows {2hh, 2hh+1}; wave shfl + Sd[16][2].
// Phase C: thread = (v-pair t&255, k-quarter t>>8); 4 partials combined via
//          Ubuf as Pc[3][4][256] float2 (Sacc is dead by then).
// LDS: 4+1+8+24+eps = 37.2 KB, 1 block of 1024 thr per CU.
// ---------------------------------------------------------------------------
__global__ __launch_bounds__(1024) void attn_kernel(
        const float* __restrict__ Eq, const float* __restrict__ Ekp,
        const float* __restrict__ Wv, const int* __restrict__ valid_lens,
        const float* __restrict__ values, float* __restrict__ out) {
    __shared__ __align__(16) float Eqs[4][256];   // 4 KB
    __shared__ float Wvs[256];                    // 1 KB
    __shared__ __align__(16) float P[4][512];     // 8 KB
    __shared__ float Sd[16][2];                   // wave partial denoms
    __shared__ __align__(16) float Ubuf[6144];    // 24 KB union: Sacc / Pc

    const int t   = threadIdx.x;
    const int lid = blockIdx.x;
    // XCD-bijective remap (8 XCDs, 256 blocks): batch b pinned to XCD lid&7.
    const int r  = lid & 7;
    const int j  = lid >> 3;            // 0..31
    const int b  = r + 8 * (j & 1);     // 0..15
    const int q0 = (j >> 1) * 4;        // 0..60

    // stage Eq rows (4 x 256 floats) + Wv with the first 256 threads
    if (t < 256) {
        const float4* eq4 = reinterpret_cast<const float4*>(Eq + (size_t)(b * 64 + q0) * 256);
        *reinterpret_cast<float4*>(&Eqs[t >> 6][(t & 63) * 4]) = eq4[t];
        Wvs[t] = Wv[t];
    }
    __syncthreads();

    // ---- phase A: raw-score partial for k-col (t&511), h2-half (t>>9) ----
    const int k  = t & 511;
    const int hh = t >> 9;              // 0..1
    const float2* ekp2 = reinterpret_cast<const float2*>(Ekp)
                       + (size_t)b * 65536 + (size_t)(hh * 64) * 512 + k;
    float acc[4] = {0.f, 0.f, 0.f, 0.f};
#pragma unroll 8
    for (int i = 0; i < 64; ++i) {
        float2 ek = ekp2[i * 512];
        float2 wv = *reinterpret_cast<const float2*>(&Wvs[hh * 128 + 2 * i]);
#pragma unroll
        for (int q = 0; q < 4; ++q) {
            float2 e = *reinterpret_cast<const float2*>(&Eqs[q][hh * 128 + 2 * i]);
            float a0 = fmaf(e.x, ek.x, 1.0f);
            float a1 = fmaf(e.y, ek.y, 1.0f);
            acc[q] = fmaf(fmaf(wv.y, a0, wv.x * a1),
                          __builtin_amdgcn_rcpf(a0 * a1), acc[q]);
        }
    }
    // Sacc[hh][q][k] = Ubuf[hh*2048 + q*512 + k]
#pragma unroll
    for (int q = 0; q < 4; ++q) Ubuf[hh * 2048 + q * 512 + k] = acc[q];
    __syncthreads();

    // ---- phase B: half hh handles q-rows {2hh, 2hh+1} ----
    const int vl = valid_lens[b];
    const int qb = hh * 2;
    float E[2], part[2];
#pragma unroll
    for (int qq = 0; qq < 2; ++qq) {
        int q = qb + qq;
        float s = -2.0f * (Ubuf[q * 512 + k] + Ubuf[2048 + q * 512 + k]);
        E[qq] = (k < vl) ? __builtin_amdgcn_exp2f(s * LOG2E) : 0.0f;
        part[qq] = E[qq];
    }
#pragma unroll
    for (int off = 32; off > 0; off >>= 1)
#pragma unroll
        for (int qq = 0; qq < 2; ++qq) part[qq] += __shfl_xor(part[qq], off);
    if ((t & 63) == 0) {
        int wave = t >> 6;              // 0..15 (0-7: hh=0, 8-15: hh=1)
        Sd[wave][0] = part[0]; Sd[wave][1] = part[1];
    }
    __syncthreads();
#pragma unroll
    for (int qq = 0; qq < 2; ++qq) {
        int base = hh * 8;
        float d = ((Sd[base + 0][qq] + Sd[base + 1][qq]) + (Sd[base + 2][qq] + Sd[base + 3][qq]))
                + ((Sd[base + 4][qq] + Sd[base + 5][qq]) + (Sd[base + 6][qq] + Sd[base + 7][qq]));
        P[qb + qq][k] = E[qq] * (1.0f / d);
    }
    __syncthreads();

    // ---- phase C: PV. thread = (v-pair v2c, k-quarter kq); 128 k each ----
    const int v2c = t & 255;            // v-cols {2*v2c, 2*v2c+1}
    const int kq  = t >> 8;             // 0..3
    const int k0c = kq * 128;
    const float2* V2 = reinterpret_cast<const float2*>(values)
                     + (size_t)b * 131072 + (size_t)k0c * 256 + v2c;
    float2 av[4];
#pragma unroll
    for (int q = 0; q < 4; ++q) av[q] = make_float2(0.f, 0.f);

#pragma unroll 4
    for (int k4 = 0; k4 < 32; ++k4) {
        float2 v0 = V2[(size_t)(k4 * 4 + 0) * 256];
        float2 v1 = V2[(size_t)(k4 * 4 + 1) * 256];
        float2 v2 = V2[(size_t)(k4 * 4 + 2) * 256];
        float2 v3 = V2[(size_t)(k4 * 4 + 3) * 256];
#pragma unroll
        for (int q = 0; q < 4; ++q) {
            float4 p = *reinterpret_cast<const float4*>(&P[q][k0c + k4 * 4]);
            av[q].x = fmaf(p.x, v0.x, av[q].x); av[q].y = fmaf(p.x, v0.y, av[q].y);
            av[q].x = fmaf(p.y, v1.x, av[q].x); av[q].y = fmaf(p.y, v1.y, av[q].y);
            av[q].x = fmaf(p.z, v2.x, av[q].x); av[q].y = fmaf(p.z, v2.y, av[q].y);
            av[q].x = fmaf(p.w, v3.x, av[q].x); av[q].y = fmaf(p.w, v3.y, av[q].y);
        }
    }

    // combine 4 k-quarter partials via Pc[3][4][256] float2 (Ubuf reuse)
    float2* Pc = reinterpret_cast<float2*>(Ubuf);
    if (kq > 0) {
#pragma unroll
        for (int q = 0; q < 4; ++q) Pc[((kq - 1) * 4 + q) * 256 + v2c] = av[q];
    }
    __syncthreads();
    if (kq == 0) {
        float* ob = out + (size_t)(b * 64 + q0) * 512 + 2 * v2c;
#pragma unroll
        for (int q = 0; q < 4; ++q) {
            float2 p1 = Pc[(0 * 4 + q) * 256 + v2c];
            float2 p2 = Pc[(1 * 4 + q) * 256 + v2c];
            float2 p3 = Pc[(2 * 4 + q) * 256 + v2c];
            float2 o;
            o.x = (av[q].x + p1.x) + (p2.x + p3.x);
            o.y = (av[q].y + p1.y) + (p2.y + p3.y);
            *reinterpret_cast<float2*>(ob + (size_t)q * 512) = o;
        }
    }
}

// ---------------------------------------------------------------------------
extern "C" void kernel_launch(void* const* d_in, const int* in_sizes, int n_in,
                              void* d_out, int out_size, void* d_ws, size_t ws_size,
                              hipStream_t stream) {
    (void)in_sizes; (void)n_in; (void)out_size; (void)ws_size;
    const float* queries    = (const float*)d_in[0];   // [16,64,512]
    const float* keys       = (const float*)d_in[1];   // [16,512,512]
    const float* values     = (const float*)d_in[2];   // [16,512,512]
    const int*   valid_lens = (const int*)d_in[3];     // [16]
    const float* Wq         = (const float*)d_in[4];   // [512,256]
    const float* Wk         = (const float*)d_in[5];   // [512,256]
    const float* Wv         = (const float*)d_in[6];   // [256]
    float* out = (float*)d_out;                        // [16,64,512]

    float* ws     = (float*)d_ws;
    float* Eq     = ws;                         // [1024][256]        1 MB
    float* Ekp    = ws + 262144;                // [16][128][512][2]  8 MB
    ushort* Wq2T  = (ushort*)(ws + 2883584);    // [4][16][12][64][8] 0.75 MB
    ushort* Wk2T  = Wq2T + 393216;              // same layout        0.75 MB

    hipLaunchKernelGGL(wprep_kernel, dim3(8, 4, 2), dim3(256), 0, stream,
                       Wq, Wk, Wq2T, Wk2T);
    hipLaunchKernelGGL(mfma_proj_kernel, dim3(288, 4), dim3(256), 0, stream,
                       queries, keys, Wq2T, Wk2T, Eq, Ekp);
    hipLaunchKernelGGL(attn_kernel, dim3(256), dim3(1024), 0, stream,
                       Eq, Ekp, Wv, valid_lens, values, out);
}

// Round 8
// 139.054 us; speedup vs baseline: 1.1038x; 1.0115x over previous
//
#include <hip/hip_runtime.h>

// Problem dims: B=16, Q=64, K=512, DQ=DK=DV=512, H=256
#define LOG2E 1.4426950408889634f
#define TWO_LOG2E 2.8853900817779268f

typedef __attribute__((ext_vector_type(8))) short short8;   // bf16x8 MFMA frag
typedef __attribute__((ext_vector_type(4))) float f32x4;    // MFMA acc

__device__ __forceinline__ float e2x(float v) {
    return __builtin_amdgcn_exp2f(v * TWO_LOG2E);   // e^{2v}
}

// Exact fp32 -> (hi,lo) bf16 split, packed.
__device__ __forceinline__ void split2(float x, float y, unsigned& hi, unsigned& lo) {
    unsigned ux = __float_as_uint(x), uy = __float_as_uint(y);
    float hx = __uint_as_float(ux & 0xffff0000u);
    float hy = __uint_as_float(uy & 0xffff0000u);
    unsigned lx = __float_as_uint(x - hx), ly = __float_as_uint(y - hy);
    hi = (ux >> 16) | (uy & 0xffff0000u);
    lo = (lx >> 16) | (ly & 0xffff0000u);
}

// ---------------------------------------------------------------------------
// Kernel 0: W2T split/transposed weights (chunk-major DRAM layout, unchanged).
// ---------------------------------------------------------------------------
__global__ __launch_bounds__(256) void wprep_kernel(const float* __restrict__ Wq,
                                                    const float* __restrict__ Wk,
                                                    ushort* __restrict__ Wq2T,
                                                    ushort* __restrict__ Wk2T) {
    __shared__ float T[64][65];
    const float* W  = blockIdx.z ? Wk : Wq;
    ushort* W2T     = blockIdx.z ? Wk2T : Wq2T;
    const int t  = threadIdx.x;
    const int k0 = blockIdx.x * 64;
    const int n0 = blockIdx.y * 64;
#pragma unroll
    for (int p = 0; p < 4; ++p) {
        int u  = t + p * 256;
        int kk = u >> 4;
        int nf = (u & 15) * 4;
        float4 w = *reinterpret_cast<const float4*>(&W[(size_t)(k0 + kk) * 256 + n0 + nf]);
        T[nf + 0][kk] = w.x; T[nf + 1][kk] = w.y;
        T[nf + 2][kk] = w.z; T[nf + 3][kk] = w.w;
    }
    __syncthreads();
#pragma unroll
    for (int p = 0; p < 4; ++p) {
        int u  = t + p * 256;
        int n  = u >> 4;
        int kf = (u & 15) * 4;
        float a = T[n][kf], b = T[n][kf + 1], c = T[n][kf + 2], d = T[n][kf + 3];
        unsigned h01, l01, h23, l23;
        split2(a, b, h01, l01);
        split2(c, d, h23, l23);
        int kg   = k0 + kf;              // global k, multiple of 4
        int ng   = n0 + n;               // global n 0..255
        int tile = ng >> 6;
        int row  = ng & 63;
        int cc   = kg >> 5;
        int kpos = kg & 31;
        ushort* base = W2T + (size_t)(tile * 16 + cc) * 6144
                     + (kpos >> 3) * 512 + row * 8 + (kpos & 7);
        uint2 hi; hi.x = h01; hi.y = h23;
        uint2 lo; lo.x = l01; lo.y = l23;
        *reinterpret_cast<uint2*>(base)        = hi;   // s=0 (j = 0..3)
        *reinterpret_cast<uint2*>(base + 2048) = hi;   // s=1 (j = 4..7)
        *reinterpret_cast<uint2*>(base + 4096) = lo;   // s=2 (j = 8..11)
    }
}

// ---------------------------------------------------------------------------
// Kernel 1: fused MFMA projection (unchanged).
// ---------------------------------------------------------------------------
__global__ __launch_bounds__(256) void mfma_proj_kernel(const float* __restrict__ queries,
                                                        const float* __restrict__ keys,
                                                        const ushort* __restrict__ Wq2T,
                                                        const ushort* __restrict__ Wk2T,
                                                        float* __restrict__ Eq,
                                                        float* __restrict__ Ekp) {
    __shared__ float smemf[4736];            // 18944 B: Ah(6656) + B(12288); reused as Cs
    ushort* Ah = reinterpret_cast<ushort*>(smemf);           // [32 m][104 k'] padded
    ushort* Bl = reinterpret_cast<ushort*>(smemf) + 3328;    // [j 12][row 64][8 ushort]

    const int t    = threadIdx.x;
    const int mt   = blockIdx.x;
    const int Nb   = blockIdx.y * 64;
    const bool isQ = mt < 32;
    const int mloc = (isQ ? mt : mt - 32) * 32;
    const float4* Asrc4 = reinterpret_cast<const float4*>(isQ ? queries : keys)
                        + (size_t)mloc * 128;
    const ushort* W2T = isQ ? Wq2T : Wk2T;

    const int ln15 = t & 15;
    const int q    = (t >> 4) & 3;
    const int w    = t >> 6;
    const int wn   = w * 16;                 // wave n-offset within 64
    const int am   = t >> 3;
    const int ak   = t & 7;

    const char* gB[3];
#pragma unroll
    for (int i = 0; i < 3; ++i)
        gB[i] = reinterpret_cast<const char*>(W2T) + (size_t)(Nb >> 6) * 196608
              + i * 4096 + t * 16;

    f32x4 acc[2];
    acc[0] = (f32x4)0.0f;
    acc[1] = (f32x4)0.0f;

    float4 ra = Asrc4[(size_t)am * 128 + ak];

    for (int c = 0; c < 16; ++c) {
        __syncthreads();
#pragma unroll
        for (int i = 0; i < 3; ++i) {
            __builtin_amdgcn_global_load_lds(
                reinterpret_cast<const unsigned int*>(gB[i]),
                reinterpret_cast<unsigned int*>(
                    reinterpret_cast<char*>(smemf) + 6656 + i * 4096 + (t >> 6) * 1024),
                16, 0, 0);
            gB[i] += 12288;
        }
        {
            unsigned h01, l01, h23, l23;
            split2(ra.x, ra.y, h01, l01);
            split2(ra.z, ra.w, h23, l23);
            uint2 hi; hi.x = h01; hi.y = h23;
            uint2 lo; lo.x = l01; lo.y = l23;
            ushort* row = Ah + am * 104 + ak * 4;
            *reinterpret_cast<uint2*>(row)      = hi;   // s=0
            *reinterpret_cast<uint2*>(row + 32) = lo;   // s=1
            *reinterpret_cast<uint2*>(row + 64) = hi;   // s=2
        }
        if (c < 15) ra = Asrc4[(size_t)am * 128 + (c + 1) * 8 + ak];
        __syncthreads();
#pragma unroll
        for (int s = 0; s < 3; ++s) {
            short8 af[2], bf;
#pragma unroll
            for (int fm = 0; fm < 2; ++fm)
                af[fm] = *reinterpret_cast<const short8*>(
                    Ah + (fm * 16 + ln15) * 104 + s * 32 + q * 8);
            bf = *reinterpret_cast<const short8*>(
                Bl + (s * 4 + q) * 512 + (wn + ln15) * 8);
#pragma unroll
            for (int fm = 0; fm < 2; ++fm)
                acc[fm] = __builtin_amdgcn_mfma_f32_16x16x32_bf16(
                    af[fm], bf, acc[fm], 0, 0, 0);
        }
    }

    if (isQ) {
#pragma unroll
        for (int fm = 0; fm < 2; ++fm)
#pragma unroll
            for (int r = 0; r < 4; ++r) {
                int row = mloc + fm * 16 + q * 4 + r;
                int col = Nb + wn + ln15;
                Eq[(size_t)row * 256 + col] = e2x(acc[fm][r]);
            }
    } else {
        __syncthreads();
        float (*Cs)[33] = reinterpret_cast<float(*)[33]>(smemf);  // [n 64][m 32]
#pragma unroll
        for (int fm = 0; fm < 2; ++fm)
#pragma unroll
            for (int r = 0; r < 4; ++r) {
                int m_l = fm * 16 + q * 4 + r;
                int n_l = wn + ln15;
                Cs[n_l][m_l] = acc[fm][r];
            }
        __syncthreads();
        const int b      = mloc >> 9;
        const int k0h    = (mloc & 511) >> 1;
        const int h2base = Nb >> 1;
        float4* out4 = reinterpret_cast<float4*>(Ekp);
#pragma unroll
        for (int p = 0; p < 2; ++p) {
            int u   = t + p * 256;           // 0..511
            int h2r = u >> 4;                // 0..31
            int kp  = u & 15;                // 0..15
            int kk  = kp * 2;
            float4 o;
            o.x = e2x(Cs[2 * h2r    ][kk    ]);
            o.y = e2x(Cs[2 * h2r + 1][kk    ]);
            o.z = e2x(Cs[2 * h2r    ][kk + 1]);
            o.w = e2x(Cs[2 * h2r + 1][kk + 1]);
            out4[(size_t)b * 32768 + (size_t)(h2base + h2r) * 256 + k0h + kp] = o;
        }
    }
}

// ---------------------------------------------------------------------------
// Kernel 2: raw masked scores (R1-verified math), 1-D grid 1024 with
// XCD-bijective decode: all blocks of batch b -> XCD b&7; per-XCD footprint
// Eq(128KB) + Ekp(1MB) for 2 batches ~ 1.1 MB (L2-resident).
// Block = 256 thr = 64 k-lanes x 4 h-quarters; 8 q-rows per block.
// ---------------------------------------------------------------------------
__global__ __launch_bounds__(256) void score_raw_kernel(
        const float* __restrict__ Eq, const float* __restrict__ Ekp,
        const float* __restrict__ Wv, const int* __restrict__ valid_lens,
        float* __restrict__ scores) {
    __shared__ float Eqs[8][256];     // 8 KB
    __shared__ float Wvs[256];        // 1 KB
    __shared__ float Sh[4][8][64];    // 8 KB
    const int t   = threadIdx.x;
    const int lid = blockIdx.x;       // 0..1023
    // XCD-bijective decode: xcd = lid&7 (HW round-robin), batch pinned to it.
    const int r    = lid & 7;
    const int u    = lid >> 3;        // 0..127
    const int b    = r + 8 * (u & 1); // 0..15
    const int rest = u >> 1;          // 0..63
    const int q0   = (rest & 7) * 8;
    const int kb   = (rest >> 3) * 64;

    const float4* eq4 = reinterpret_cast<const float4*>(Eq + (size_t)(b * 64 + q0) * 256);
#pragma unroll
    for (int i = 0; i < 2; ++i) {
        int uu = t + i * 256;         // 0..511: row = uu>>6, col4 = uu&63
        *reinterpret_cast<float4*>(&Eqs[uu >> 6][(uu & 63) * 4]) = eq4[uu];
    }
    Wvs[t] = Wv[t];
    __syncthreads();

    const int kl = t & 63;            // k_local 0..63
    const int hh = t >> 6;            // h-quarter 0..3
    const float2* ek2 = reinterpret_cast<const float2*>(Ekp)
                      + (size_t)b * 65536 + (size_t)(hh * 32) * 512 + kb + kl;

    float acc[8] = {0.f, 0.f, 0.f, 0.f, 0.f, 0.f, 0.f, 0.f};
#pragma unroll 4
    for (int i = 0; i < 32; ++i) {
        float2 ek = ek2[(size_t)i * 512];
        int h2 = hh * 32 + i;
        float2 wv = *reinterpret_cast<const float2*>(&Wvs[2 * h2]);
#pragma unroll
        for (int q = 0; q < 8; ++q) {
            float2 e = *reinterpret_cast<const float2*>(&Eqs[q][2 * h2]);
            float a0 = fmaf(e.x, ek.x, 1.0f);
            float a1 = fmaf(e.y, ek.y, 1.0f);
            float d  = a0 * a1;
            float n  = fmaf(wv.y, a0, wv.x * a1);
            acc[q] = fmaf(n, __builtin_amdgcn_rcpf(d), acc[q]);
        }
    }
#pragma unroll
    for (int q = 0; q < 8; ++q) Sh[hh][q][kl] = acc[q];
    __syncthreads();

    const int vl = valid_lens[b];
#pragma unroll
    for (int i = 0; i < 2; ++i) {
        int uu = t + i * 256;         // 0..511
        int q = uu >> 6, k = uu & 63;
        float s = -2.0f * ((Sh[0][q][k] + Sh[1][q][k]) + (Sh[2][q][k] + Sh[3][q][k]));
        if (kb + k >= vl) s = -1e6f;
        scores[(size_t)(b * 64 + q0 + q) * 512 + kb + k] = s;
    }
}

// ---------------------------------------------------------------------------
// Kernel 3: fused softmax + out = P @ values (R1-verified math), 1-D grid 512
// with XCD-bijective decode (V[b]+scores[b] L2-pinned: ~2.3 MB/XCD).
// Block = 256 thr; q-tile 16, v-tile 64; Ps[16][516] + Vs[2][32][64] dbuf.
// ---------------------------------------------------------------------------
__global__ __launch_bounds__(256) void pv_kernel(const float* __restrict__ scores,
                                                 const float* __restrict__ values,
                                                 float* __restrict__ out) {
    __shared__ __align__(16) float Ps[16][516];    // 33024 B
    __shared__ __align__(16) float Vs[2][32][64];  // 2 x 8192 B

    const int t   = threadIdx.x;
    const int lid = blockIdx.x;       // 0..511
    const int r    = lid & 7;
    const int u    = lid >> 3;        // 0..63
    const int b    = r + 8 * (u & 1); // 0..15
    const int rest = u >> 1;          // 0..31
    const int q0   = (rest & 3) * 16;
    const int vt   = rest >> 2;       // 0..7

    const float4* sc4 = reinterpret_cast<const float4*>(scores) + (size_t)(b * 64 + q0) * 128;
#pragma unroll
    for (int p = 0; p < 8; ++p) {
        int uu = t + p * 256;        // 0..2047
        int qr = uu >> 7;            // 0..15
        int c4 = uu & 127;
        *reinterpret_cast<float4*>(&Ps[qr][c4 * 4]) = sc4[(size_t)qr * 128 + c4];
    }

    // V staging: chunk = 32 k x 64 v x 4 B = 8 KB = 2 glds x 4096 B.
    const char* vbase = reinterpret_cast<const char*>(values)
                      + ((size_t)b * 512 * 512 + (size_t)vt * 64) * 4
                      + (size_t)(t >> 4) * 2048 + (size_t)(t & 15) * 16;
    char* ldsV0 = reinterpret_cast<char*>(&Vs[0][0][0]) + (t >> 6) * 1024;

    const int lane = t & 63;
    const int w    = t >> 6;                       // wave -> q-rows 4w..4w+3
    const int v4   = lane & 15;
    const int ksub = lane >> 4;                    // 0..3

    // issue chunk 0 into buffer 0
#pragma unroll
    for (int i = 0; i < 2; ++i)
        __builtin_amdgcn_global_load_lds(
            reinterpret_cast<const unsigned int*>(vbase + (size_t)i * 32768),
            reinterpret_cast<unsigned int*>(ldsV0 + i * 4096), 16, 0, 0);
    __syncthreads();                               // Ps + chunk0 ready

    // ---- per-wave softmax on own 4 rows ----
#pragma unroll
    for (int rr = 0; rr < 4; ++rr) {
        const int rq = 4 * w + rr;
        float v[8];
        float m = -1e30f;
#pragma unroll
        for (int i = 0; i < 8; ++i) { v[i] = Ps[rq][lane + i * 64]; m = fmaxf(m, v[i]); }
#pragma unroll
        for (int off = 32; off > 0; off >>= 1) m = fmaxf(m, __shfl_xor(m, off));
        float s = 0.f;
#pragma unroll
        for (int i = 0; i < 8; ++i) {
            v[i] = __builtin_amdgcn_exp2f((v[i] - m) * LOG2E);
            s += v[i];
        }
#pragma unroll
        for (int off = 32; off > 0; off >>= 1) s += __shfl_xor(s, off);
        float inv = 1.0f / s;
#pragma unroll
        for (int i = 0; i < 8; ++i) Ps[rq][lane + i * 64] = v[i] * inv;
    }

    float4 acc[4];
#pragma unroll
    for (int rq = 0; rq < 4; ++rq) acc[rq] = make_float4(0.f, 0.f, 0.f, 0.f);

    for (int c = 0; c < 16; ++c) {
        if (c < 15) {
            char* dst = reinterpret_cast<char*>(&Vs[(c + 1) & 1][0][0]) + (t >> 6) * 1024;
            const char* src = vbase + (size_t)(c + 1) * 65536;
#pragma unroll
            for (int i = 0; i < 2; ++i)
                __builtin_amdgcn_global_load_lds(
                    reinterpret_cast<const unsigned int*>(src + (size_t)i * 32768),
                    reinterpret_cast<unsigned int*>(dst + i * 4096), 16, 0, 0);
        }

        const float (*V)[64] = Vs[c & 1];
#pragma unroll
        for (int kk = 0; kk < 2; ++kk) {
            int kbs = kk * 16 + ksub * 4;
            float4 V0 = *reinterpret_cast<const float4*>(&V[kbs + 0][v4 * 4]);
            float4 V1 = *reinterpret_cast<const float4*>(&V[kbs + 1][v4 * 4]);
            float4 V2 = *reinterpret_cast<const float4*>(&V[kbs + 2][v4 * 4]);
            float4 V3 = *reinterpret_cast<const float4*>(&V[kbs + 3][v4 * 4]);
#pragma unroll
            for (int rq = 0; rq < 4; ++rq) {
                float4 p = *reinterpret_cast<const float4*>(&Ps[4 * w + rq][c * 32 + kbs]);
                acc[rq].x = fmaf(p.x, V0.x, acc[rq].x); acc[rq].y = fmaf(p.x, V0.y, acc[rq].y);
                acc[rq].z = fmaf(p.x, V0.z, acc[rq].z); acc[rq].w = fmaf(p.x, V0.w, acc[rq].w);
                acc[rq].x = fmaf(p.y, V1.x, acc[rq].x); acc[rq].y = fmaf(p.y, V1.y, acc[rq].y);
                acc[rq].z = fmaf(p.y, V1.z, acc[rq].z); acc[rq].w = fmaf(p.y, V1.w, acc[rq].w);
                acc[rq].x = fmaf(p.z, V2.x, acc[rq].x); acc[rq].y = fmaf(p.z, V2.y, acc[rq].y);
                acc[rq].z = fmaf(p.z, V2.z, acc[rq].z); acc[rq].w = fmaf(p.z, V2.w, acc[rq].w);
                acc[rq].x = fmaf(p.w, V3.x, acc[rq].x); acc[rq].y = fmaf(p.w, V3.y, acc[rq].y);
                acc[rq].z = fmaf(p.w, V3.z, acc[rq].z); acc[rq].w = fmaf(p.w, V3.w, acc[rq].w);
            }
        }
        __syncthreads();
    }

    // combine 4 ksub partials (butterfly over lane bits 4,5)
#pragma unroll
    for (int off = 16; off <= 32; off <<= 1)
#pragma unroll
        for (int rq = 0; rq < 4; ++rq) {
            acc[rq].x += __shfl_xor(acc[rq].x, off); acc[rq].y += __shfl_xor(acc[rq].y, off);
            acc[rq].z += __shfl_xor(acc[rq].z, off); acc[rq].w += __shfl_xor(acc[rq].w, off);
        }
    if (ksub == 0) {
        float4* out4 = reinterpret_cast<float4*>(out);
#pragma unroll
        for (int rq = 0; rq < 4; ++rq)
            out4[(size_t)(b * 64 + q0 + 4 * w + rq) * 128 + vt * 16 + v4] = acc[rq];
    }
}

// ---------------------------------------------------------------------------
extern "C" void kernel_launch(void* const* d_in, const int* in_sizes, int n_in,
                              void* d_out, int out_size, void* d_ws, size_t ws_size,
                              hipStream_t stream) {
    (void)in_sizes; (void)n_in; (void)out_size; (void)ws_size;
    const float* queries    = (const float*)d_in[0];   // [16,64,512]
    const float* keys       = (const float*)d_in[1];   // [16,512,512]
    const float* values     = (const float*)d_in[2];   // [16,512,512]
    const int*   valid_lens = (const int*)d_in[3];     // [16]
    const float* Wq         = (const float*)d_in[4];   // [512,256]
    const float* Wk         = (const float*)d_in[5];   // [512,256]
    const float* Wv         = (const float*)d_in[6];   // [256]
    float* out = (float*)d_out;                        // [16,64,512]

    float* ws     = (float*)d_ws;
    float* Eq     = ws;                         // [1024][256]        1 MB
    float* Ekp    = ws + 262144;                // [16][128][512][2]  8 MB
    float* scores = ws + 262144 + 2097152;      // [16][64][512]      2 MB
    ushort* Wq2T  = (ushort*)(ws + 2883584);    // [4][16][12][64][8] 0.75 MB
    ushort* Wk2T  = Wq2T + 393216;              // same layout        0.75 MB

    hipLaunchKernelGGL(wprep_kernel, dim3(8, 4, 2), dim3(256), 0, stream,
                       Wq, Wk, Wq2T, Wk2T);
    hipLaunchKernelGGL(mfma_proj_kernel, dim3(288, 4), dim3(256), 0, stream,
                       queries, keys, Wq2T, Wk2T, Eq, Ekp);
    hipLaunchKernelGGL(score_raw_kernel, dim3(1024), dim3(256), 0, stream,
                       Eq, Ekp, Wv, valid_lens, scores);
    hipLaunchKernelGGL(pv_kernel, dim3(512), dim3(256), 0, stream,
                       scores, values, out);
}